// Round 1
// baseline (128.309 us; speedup 1.0000x reference)
//
#include <hip/hip_runtime.h>

#define EDGES 1600000
#define NN 100000
#define ZD 64
#define FD 16
#define KDIM 144      // 2*ZD + FD
#define KP 160        // K padded to multiple of 32
#define HID 128
#define BM 64         // edges per tile
#define SSTR 168      // LDS row stride in bf16 elems (336 B, 16B-aligned, %32dw=20)
#define THREADS 256
#define NBLK 512      // 2 blocks / CU, persistent

typedef __attribute__((ext_vector_type(8))) short bfrag;   // 8 bf16 = 4 VGPR
typedef __attribute__((ext_vector_type(4))) float ffrag;   // 4 f32 acc

__device__ __forceinline__ unsigned short f2bf(float f) {
  unsigned u = __builtin_bit_cast(unsigned, f);
  u += 0x7fffu + ((u >> 16) & 1u);   // round-to-nearest-even
  return (unsigned short)(u >> 16);
}

__global__ void zconv_kernel(const float* __restrict__ z,
                             unsigned short* __restrict__ z16, int n4) {
  int i = blockIdx.x * blockDim.x + threadIdx.x;
  if (i >= n4) return;
  float4 f = reinterpret_cast<const float4*>(z)[i];
  ushort4 p;
  p.x = f2bf(f.x); p.y = f2bf(f.y); p.z = f2bf(f.z); p.w = f2bf(f.w);
  reinterpret_cast<ushort4*>(z16)[i] = p;
}

template<bool ZB>
__global__ __launch_bounds__(THREADS, 2) void fused_kernel(
    const float* __restrict__ zf, const unsigned short* __restrict__ z16,
    const int* __restrict__ ei, const float* __restrict__ ea,
    const float* __restrict__ W1, const float* __restrict__ b1,
    const float* __restrict__ W2, const float* __restrict__ b2,
    float* __restrict__ out)
{
  __shared__ __align__(16) unsigned short sW[HID][SSTR];  // W1^T: sW[n][k]
  __shared__ __align__(16) unsigned short sA[BM][SSTR];   // edge-input tile (bf16)
  __shared__ float sb1[HID];
  __shared__ float sW2[HID];

  const int tid = threadIdx.x;
  const int lane = tid & 63;
  const int wid = tid >> 6;
  const int col = lane & 15;
  const int kq = lane >> 4;

  // ---- W1^T -> LDS (bf16), zero-padded K rows 144..159 ----
  for (int i = tid; i < HID * KP; i += THREADS) {
    int n = i & (HID - 1);
    int k = i >> 7;
    float v = (k < KDIM) ? W1[k * HID + n] : 0.f;
    sW[n][k] = f2bf(v);
  }
  if (tid < HID) { sb1[tid] = b1[tid]; sW2[tid] = W2[tid]; }
  // zero the K-pad columns of sA (144..159) once; never overwritten
  for (int i = tid; i < BM * 2; i += THREADS) {
    int r = i >> 1, q = i & 1;
    *reinterpret_cast<int4*>(&sA[r][KDIM + q * 8]) = int4{0, 0, 0, 0};
  }
  __syncthreads();

  // ---- preload all B fragments into registers (tile-invariant) ----
  // B[k][j] = W1[k][n*16+j] = sW[n*16+j][k]; lane j=col, k = kq*8..+8 per ks
  bfrag Bf[5][8];
  #pragma unroll
  for (int ks = 0; ks < 5; ++ks)
    #pragma unroll
    for (int n = 0; n < 8; ++n)
      Bf[ks][n] = *reinterpret_cast<const bfrag*>(&sW[n * 16 + col][ks * 32 + kq * 8]);

  float w2r[8], b1r[8];
  #pragma unroll
  for (int n = 0; n < 8; ++n) { w2r[n] = sW2[n * 16 + col]; b1r[n] = sb1[n * 16 + col]; }
  const float bias2 = b2[0];

  const int ntiles = EDGES / BM;   // 25000, E divisible by BM -> no tail
  for (int tile = blockIdx.x; tile < ntiles; tile += gridDim.x) {
    const int base = tile * BM;
    __syncthreads();   // previous tile's sA readers are done

    // ---- gather: 4 threads per edge stage one 160-col bf16 row ----
    {
      const int edge = tid >> 2;          // 0..63
      const int which = (tid >> 1) & 1;   // 0=src,1=dst
      const int hh = tid & 1;             // half of the 64 z elems
      const int node = ei[which * EDGES + base + edge];
      unsigned short* dst = &sA[edge][which * 64 + hh * 32];
      if (ZB) {
        const int4* sp = reinterpret_cast<const int4*>(z16 + node * ZD + hh * 32);
        int4 v0 = sp[0], v1 = sp[1], v2 = sp[2], v3 = sp[3];
        int4* dp = reinterpret_cast<int4*>(dst);
        dp[0] = v0; dp[1] = v1; dp[2] = v2; dp[3] = v3;
      } else {
        const float4* sp = reinterpret_cast<const float4*>(zf + node * ZD + hh * 32);
        #pragma unroll
        for (int j = 0; j < 4; ++j) {
          float4 a = sp[2 * j], bq = sp[2 * j + 1];
          ushort4 lo, hi;
          lo.x = f2bf(a.x);  lo.y = f2bf(a.y);  lo.z = f2bf(a.z);  lo.w = f2bf(a.w);
          hi.x = f2bf(bq.x); hi.y = f2bf(bq.y); hi.z = f2bf(bq.z); hi.w = f2bf(bq.w);
          reinterpret_cast<ushort4*>(dst)[2 * j]     = lo;
          reinterpret_cast<ushort4*>(dst)[2 * j + 1] = hi;
        }
      }
    }
    {
      const int edge = tid >> 2;
      const int q = tid & 3;
      float4 f = *reinterpret_cast<const float4*>(ea + (size_t)(base + edge) * FD + q * 4);
      ushort4 p;
      p.x = f2bf(f.x); p.y = f2bf(f.y); p.z = f2bf(f.z); p.w = f2bf(f.w);
      *reinterpret_cast<ushort4*>(&sA[edge][2 * ZD + q * 4]) = p;
    }
    __syncthreads();

    // ---- MFMA: wave strip = 16 rows x 128 cols ----
    ffrag acc[8];
    #pragma unroll
    for (int n = 0; n < 8; ++n) acc[n] = ffrag{0.f, 0.f, 0.f, 0.f};
    const int rowb = wid * 16 + col;     // A row i = lane&15
    #pragma unroll
    for (int ks = 0; ks < 5; ++ks) {
      bfrag a = *reinterpret_cast<const bfrag*>(&sA[rowb][ks * 32 + kq * 8]);
      #pragma unroll
      for (int n = 0; n < 8; ++n)
        acc[n] = __builtin_amdgcn_mfma_f32_16x16x32_bf16(a, Bf[ks][n], acc[n], 0, 0, 0);
    }

    // ---- epilogue: ReLU, dot W2, reduce across 16 cols, sigmoid ----
    // D layout: col j = lane&15, row = kq*4 + r
    float sv[4];
    #pragma unroll
    for (int r = 0; r < 4; ++r) {
      float p = 0.f;
      #pragma unroll
      for (int n = 0; n < 8; ++n) {
        float h = acc[n][r] + b1r[n];
        h = fmaxf(h, 0.f);
        p = fmaf(h, w2r[n], p);
      }
      p += __shfl_xor(p, 1);
      p += __shfl_xor(p, 2);
      p += __shfl_xor(p, 4);
      p += __shfl_xor(p, 8);
      sv[r] = p;
    }
    if (col == 0) {
      const int row = base + wid * 16 + kq * 4;
      float4 o;
      o.x = 1.f / (1.f + __expf(-(sv[0] + bias2)));
      o.y = 1.f / (1.f + __expf(-(sv[1] + bias2)));
      o.z = 1.f / (1.f + __expf(-(sv[2] + bias2)));
      o.w = 1.f / (1.f + __expf(-(sv[3] + bias2)));
      *reinterpret_cast<float4*>(out + row) = o;
    }
  }
}

extern "C" void kernel_launch(void* const* d_in, const int* in_sizes, int n_in,
                              void* d_out, int out_size, void* d_ws, size_t ws_size,
                              hipStream_t stream) {
  const float* z  = (const float*)d_in[0];
  const int*   ei = (const int*)d_in[1];
  const float* ea = (const float*)d_in[2];
  const float* W1 = (const float*)d_in[3];
  const float* b1 = (const float*)d_in[4];
  const float* W2 = (const float*)d_in[5];
  const float* b2 = (const float*)d_in[6];
  float* out = (float*)d_out;

  const size_t z16_bytes = (size_t)NN * ZD * sizeof(unsigned short);
  if (ws_size >= z16_bytes) {
    unsigned short* z16 = (unsigned short*)d_ws;
    const int n4 = NN * ZD / 4;
    zconv_kernel<<<(n4 + 255) / 256, 256, 0, stream>>>(z, z16, n4);
    fused_kernel<true><<<NBLK, THREADS, 0, stream>>>(z, z16, ei, ea, W1, b1, W2, b2, out);
  } else {
    fused_kernel<false><<<NBLK, THREADS, 0, stream>>>(z, nullptr, ei, ea, W1, b1, W2, b2, out);
  }
}